// Round 1
// baseline (108.914 us; speedup 1.0000x reference)
//
#include <hip/hip_runtime.h>
#include <hip/hip_bf16.h>
#include <math.h>

#define NSUP 512
#define DLAT 128
#define DHID 512
#define DIN  64
#define BR   16
#define PAD  20   // LDS row stride in floats: 80B, keeps 16B alignment, breaks bank cycling on writes

// ---------------- prep: transposes + support trig + norms ----------------
__global__ void prep_kernel(const float* __restrict__ W1, const float* __restrict__ W2,
                            const float* __restrict__ support,
                            float* __restrict__ W1T, float* __restrict__ W2T,
                            float4* __restrict__ scd, float* __restrict__ sn2)
{
    int idx = blockIdx.x * blockDim.x + threadIdx.x;   // 0..65535
    if (idx < DHID * DIN) {                 // W1 [512][64] -> W1T [64][512]
        int c = idx / DIN, k = idx % DIN;
        W1T[k * DHID + c] = W1[idx];
    }
    {                                        // W2 [128][512] -> W2T [512][128]
        int j = idx / DHID, k = idx % DHID;
        W2T[k * DLAT + j] = W2[idx];
    }
    {                                        // support [512][128] -> scd[i][s] = {s, cos(s/2), sin(s/2), 0}
        int s = idx / DLAT, i = idx % DLAT;
        float v = support[idx];
        scd[i * NSUP + s] = make_float4(v, cosf(0.5f * v), sinf(0.5f * v), 0.f);
    }
    if (idx < NSUP) {                        // ||s||^2
        float acc = 0.f;
        for (int i = 0; i < DLAT; i++) { float v = support[idx * DLAT + i]; acc = fmaf(v, v, acc); }
        sn2[idx] = acc;
    }
}

// ---------------- fused main kernel ----------------
__global__ __launch_bounds__(512) void fused_kernel(
    const float* __restrict__ x, const float* __restrict__ b1, const float* __restrict__ b2,
    const float* __restrict__ W1T, const float* __restrict__ W2T,
    const float4* __restrict__ scd, const float* __restrict__ sn2,
    const float* __restrict__ wts, float* __restrict__ out)
{
    __shared__ float xT[DIN][PAD];     //  5 KB  xT[k][r]
    __shared__ float hT[DHID][PAD];    // 40 KB  hT[k][r]
    __shared__ float lT[DLAT][PAD];    // 10 KB  latent
    __shared__ float aT[DLAT][PAD];    // 10 KB  cos(l/2)
    __shared__ float bT[DLAT][PAD];    // 10 KB  sin(l/2)
    __shared__ float ln2s[BR];
    __shared__ float red2[8][4];
    __shared__ float redw[8][BR];

    const int tid  = threadIdx.x;
    const int row0 = blockIdx.x * BR;

    // ---- load x tile transposed ----
    for (int t = tid; t < BR * DIN; t += 512) {
        int r = t >> 6, k = t & 63;
        xT[k][r] = x[(row0 + r) * DIN + k];
    }
    __syncthreads();

    // ---- GEMM1 + bias + tanh: h[r][c], c = tid ----
    {
        float acc[BR];
        #pragma unroll
        for (int r = 0; r < BR; r++) acc[r] = 0.f;
        for (int k = 0; k < DIN; k++) {
            float w = W1T[k * DHID + tid];
            #pragma unroll
            for (int q = 0; q < 4; q++) {
                float4 xv = *(const float4*)&xT[k][4 * q];
                acc[4*q+0] = fmaf(xv.x, w, acc[4*q+0]);
                acc[4*q+1] = fmaf(xv.y, w, acc[4*q+1]);
                acc[4*q+2] = fmaf(xv.z, w, acc[4*q+2]);
                acc[4*q+3] = fmaf(xv.w, w, acc[4*q+3]);
            }
        }
        float bb = b1[tid];
        #pragma unroll
        for (int r = 0; r < BR; r++) hT[tid][r] = tanhf(acc[r] + bb);
    }
    __syncthreads();

    // ---- GEMM2: latent[r][c], c = tid&127, 4 rows per thread ----
    const int c  = tid & (DLAT - 1);
    const int rg = tid >> 7;                  // 0..3 -> rows rg*4 .. rg*4+3
    {
        float acc[4] = {0.f, 0.f, 0.f, 0.f};
        for (int k = 0; k < DHID; k++) {
            float w = W2T[k * DLAT + c];
            float4 hv = *(const float4*)&hT[k][4 * rg];
            acc[0] = fmaf(hv.x, w, acc[0]);
            acc[1] = fmaf(hv.y, w, acc[1]);
            acc[2] = fmaf(hv.z, w, acc[2]);
            acc[3] = fmaf(hv.w, w, acc[3]);
        }
        float bb = b2[c];
        float l2[4];
        #pragma unroll
        for (int rr = 0; rr < 4; rr++) {
            float l = acc[rr] + bb;
            lT[c][rg * 4 + rr] = l;
            aT[c][rg * 4 + rr] = cosf(0.5f * l);
            bT[c][rg * 4 + rr] = sinf(0.5f * l);
            l2[rr] = l * l;
        }
        // ||l||^2 per row: wave-reduce (each wave covers 64 consecutive c, fixed rg)
        #pragma unroll
        for (int rr = 0; rr < 4; rr++) {
            float v = l2[rr];
            for (int off = 32; off; off >>= 1) v += __shfl_down(v, off);
            if ((tid & 63) == 0) red2[tid >> 6][rr] = v;
        }
    }
    __syncthreads();
    if (tid < BR) {
        int g = tid >> 2, rr = tid & 3;       // row = g*4+rr, contributed by waves 2g, 2g+1
        ln2s[tid] = red2[2 * g][rr] + red2[2 * g + 1][rr];
    }
    __syncthreads();

    // ---- Stage B: lane = support s = tid; 16 rows per thread ----
    float dot[BR], prod[BR];
    #pragma unroll
    for (int r = 0; r < BR; r++) { dot[r] = 0.f; prod[r] = 1.f; }

    for (int i = 0; i < DLAT; i++) {
        float4 sc = scd[i * NSUP + tid];      // {s_i, cos(s_i/2), sin(s_i/2), -}
        float sv = sc.x, cv = sc.y, dv = sc.z;
        #pragma unroll
        for (int q = 0; q < 4; q++) {
            float4 lv = *(const float4*)&lT[i][4 * q];
            float4 av = *(const float4*)&aT[i][4 * q];
            float4 bv = *(const float4*)&bT[i][4 * q];
            dot[4*q+0] = fmaf(lv.x, sv, dot[4*q+0]);
            dot[4*q+1] = fmaf(lv.y, sv, dot[4*q+1]);
            dot[4*q+2] = fmaf(lv.z, sv, dot[4*q+2]);
            dot[4*q+3] = fmaf(lv.w, sv, dot[4*q+3]);
            float t0 = fmaf(av.x, cv, bv.x * dv);
            float t1 = fmaf(av.y, cv, bv.y * dv);
            float t2 = fmaf(av.z, cv, bv.z * dv);
            float t3 = fmaf(av.w, cv, bv.w * dv);
            prod[4*q+0] *= t0;
            prod[4*q+1] *= t1;
            prod[4*q+2] *= t2;
            prod[4*q+3] *= t3;
        }
    }

    // ---- epilogue: kernels + weighted reduce over supports ----
    float wgt = wts[tid];
    float sn  = sn2[tid];
    #pragma unroll
    for (int r = 0; r < BR; r++) {
        float sq = ln2s[r] + sn - 2.f * dot[r];
        float kc = __expf(-sq);               // GAMMA = 1
        float p  = prod[r];
        float v  = (0.5f * kc + 0.5f * (p * p)) * wgt;
        for (int off = 32; off; off >>= 1) v += __shfl_down(v, off);
        if ((tid & 63) == 0) redw[tid >> 6][r] = v;
    }
    __syncthreads();
    if (tid < BR) {
        float o = 0.f;
        #pragma unroll
        for (int w = 0; w < 8; w++) o += redw[w][tid];
        out[row0 + tid] = o;
    }
}

// ---------------- launch ----------------
extern "C" void kernel_launch(void* const* d_in, const int* in_sizes, int n_in,
                              void* d_out, int out_size, void* d_ws, size_t ws_size,
                              hipStream_t stream) {
    const float* x       = (const float*)d_in[0];
    const float* W1      = (const float*)d_in[1];
    const float* b1      = (const float*)d_in[2];
    const float* W2      = (const float*)d_in[3];
    const float* b2      = (const float*)d_in[4];
    const float* support = (const float*)d_in[5];
    const float* wts     = (const float*)d_in[6];
    float* out = (float*)d_out;

    float* ws   = (float*)d_ws;
    float* W1T  = ws;                       // 32768
    float* W2T  = W1T + 32768;              // 65536
    float* sn2  = W2T + 65536;              // 512
    // float4 region, 16B aligned (offset so far = 98816 floats = 395264 B, multiple of 16)
    float4* scd = (float4*)(sn2 + 512);     // 65536 float4 = 1 MB

    prep_kernel<<<256, 256, 0, stream>>>(W1, W2, support, W1T, W2T, scd, sn2);
    fused_kernel<<<256, 512, 0, stream>>>(x, b1, b2, W1T, W2T, scd, sn2, wts, out);
}

// Round 2
// 76.984 us; speedup vs baseline: 1.4147x; 1.4147x over previous
//
#include <hip/hip_runtime.h>
#include <math.h>

typedef float v2f __attribute__((ext_vector_type(2)));

#define NSUP 512
#define DLAT 128
#define DHID 512
#define DIN  64
#define BR   16
#define NTILE 256   // 4096 / BR

// ---------------- prep: transposes + packs + support trig + norms ----------------
__global__ __launch_bounds__(512) void prep_kernel(
    const float* __restrict__ x, const float* __restrict__ W1, const float* __restrict__ W2,
    const float* __restrict__ support,
    float* __restrict__ W1T, float* __restrict__ W2T, float* __restrict__ xpack,
    float4* __restrict__ scd, float* __restrict__ sn2)
{
    int idx = blockIdx.x * 512 + threadIdx.x;          // 512 blocks x 512 thr = 262144
    {   // xpack[t][k][r] = x[(t*16+r)][k]
        int t = idx >> 10, rem = idx & 1023, k = rem >> 4, r = rem & 15;
        xpack[idx] = x[((t << 4) | r) * DIN + k];
    }
    if (idx < DHID * DIN) {                 // W1 [512][64] -> W1T [64][512]
        int c = idx / DIN, k = idx % DIN;
        W1T[k * DHID + c] = W1[idx];
    }
    if (idx < DLAT * DHID) {                // W2 [128][512] -> W2T [512][128]
        int j = idx / DHID, k = idx % DHID;
        W2T[k * DLAT + j] = W2[idx];
        int s = idx / DLAT, i = idx % DLAT; // support [512][128] -> scd[i][s]
        float v = support[idx];
        scd[i * NSUP + s] = make_float4(v, cosf(0.5f * v), sinf(0.5f * v), 0.f);
    }
    if (idx < NSUP) {                       // ||s||^2
        float acc = 0.f;
        for (int i = 0; i < DLAT; i++) { float v = support[idx * DLAT + i]; acc = fmaf(v, v, acc); }
        sn2[idx] = acc;
    }
}

// ---------------- GEMM1: h = tanh(x @ W1^T + b1), packed k-major ----------------
// grid 256, block 1024.  thread: hidden col c = tid&511, row-half = tid>>9 (8 rows)
__global__ __launch_bounds__(1024) void gemm1_kernel(
    const float* __restrict__ W1T, const float* __restrict__ b1,
    const float* __restrict__ xpack, float* __restrict__ hpack)
{
    const int t = blockIdx.x;
    const int c = threadIdx.x & (DHID - 1);
    const int rhalf = __builtin_amdgcn_readfirstlane(threadIdx.x >> 9);   // wave-uniform
    const float* __restrict__ xr = xpack + t * (DIN * BR) + rhalf * 8;    // uniform base

    v2f acc[4];
    #pragma unroll
    for (int q = 0; q < 4; q++) acc[q] = (v2f)(0.f);

    for (int k = 0; k < DIN; k++) {
        float w = W1T[k * DHID + c];
        v2f wv = {w, w};
        const float* xk = xr + k * BR;                 // uniform -> s_load
        #pragma unroll
        for (int q = 0; q < 4; q++) {
            v2f xv = {xk[2 * q], xk[2 * q + 1]};
            acc[q] = __builtin_elementwise_fma(xv, wv, acc[q]);
        }
    }
    float bb = b1[c];
    float* hp = hpack + t * (DHID * BR) + c * BR + rhalf * 8;
    #pragma unroll
    for (int q = 0; q < 4; q++) {
        hp[2 * q]     = tanhf(acc[q].x + bb);
        hp[2 * q + 1] = tanhf(acc[q].y + bb);
    }
}

// ---------------- GEMM2: latent = h @ W2^T + b2; writes l,cos,sin packed + ||l||^2 ----------------
// grid 256, block 1024.  thread: latent col j = tid&127, k-group g = tid>>7 (64 k each)
__global__ __launch_bounds__(1024) void gemm2_kernel(
    const float* __restrict__ W2T, const float* __restrict__ b2,
    const float* __restrict__ hpack, float* __restrict__ rowpack, float* __restrict__ ln2s)
{
    __shared__ float part[8][DLAT][17];    // 69632 B, padded stride 17 (conflict-free)
    __shared__ float l2red[16][2];

    const int t = blockIdx.x;
    const int j = threadIdx.x & (DLAT - 1);
    const int g = __builtin_amdgcn_readfirstlane(threadIdx.x >> 7);      // wave-uniform
    const float* __restrict__ hrow = hpack + t * (DHID * BR);

    v2f acc[8];
    #pragma unroll
    for (int q = 0; q < 8; q++) acc[q] = (v2f)(0.f);

    for (int kk = 0; kk < 64; kk++) {
        int k = g * 64 + kk;
        float w = W2T[k * DLAT + j];
        v2f wv = {w, w};
        const float* hk = hrow + k * BR;               // uniform -> s_load_dwordx16
        #pragma unroll
        for (int q = 0; q < 8; q++) {
            v2f hv = {hk[2 * q], hk[2 * q + 1]};
            acc[q] = __builtin_elementwise_fma(hv, wv, acc[q]);
        }
    }
    #pragma unroll
    for (int q = 0; q < 8; q++) {
        part[g][j][2 * q]     = acc[q].x;
        part[g][j][2 * q + 1] = acc[q].y;
    }
    __syncthreads();

    // reduce over the 8 k-groups; thread -> (j, row-pair rp)
    const int rp = g;                                   // reuse 0..7
    float s0 = 0.f, s1 = 0.f;
    #pragma unroll
    for (int g2 = 0; g2 < 8; g2++) {
        s0 += part[g2][j][2 * rp];
        s1 += part[g2][j][2 * rp + 1];
    }
    float bb = b2[j];
    float l0 = s0 + bb, l1 = s1 + bb;

    float* rpk = rowpack + t * (DLAT * 48) + j * 48;    // [l[16] | a[16] | b[16]]
    rpk[2 * rp]          = l0;
    rpk[2 * rp + 1]      = l1;
    rpk[16 + 2 * rp]     = cosf(0.5f * l0);
    rpk[16 + 2 * rp + 1] = cosf(0.5f * l1);
    rpk[32 + 2 * rp]     = sinf(0.5f * l0);
    rpk[32 + 2 * rp + 1] = sinf(0.5f * l1);

    // ||l||^2 per row: wave-reduce over j (64 lanes), two waves per (rp)
    const int wv = __builtin_amdgcn_readfirstlane(threadIdx.x >> 6);
    float v0 = l0 * l0, v1 = l1 * l1;
    for (int off = 32; off; off >>= 1) { v0 += __shfl_down(v0, off); v1 += __shfl_down(v1, off); }
    if ((threadIdx.x & 63) == 0) { l2red[wv][0] = v0; l2red[wv][1] = v1; }
    __syncthreads();
    if (threadIdx.x < BR) {
        int r = threadIdx.x, p = r >> 1, sel = r & 1;
        ln2s[t * BR + r] = l2red[2 * p][sel] + l2red[2 * p + 1][sel];
    }
}

// ---------------- stage B: kernels + weighted support reduction ----------------
// grid 256, block 1024 (16 waves). waves 0-7: i in [0,64); waves 8-15: i in [64,128).
// thread: support s = (wave&7)*64 + lane.
__global__ __launch_bounds__(1024) void kernelB(
    const float4* __restrict__ scd, const float* __restrict__ sn2,
    const float* __restrict__ wts, const float* __restrict__ rowpack,
    const float* __restrict__ ln2s, float* __restrict__ out)
{
    __shared__ float comb[NSUP][33];     // 67584 B, stride 33 (conflict-free)
    __shared__ float redw[8][BR];

    const int t    = blockIdx.x;
    const int wv   = __builtin_amdgcn_readfirstlane(threadIdx.x >> 6);
    const int lane = threadIdx.x & 63;
    const int half = wv >> 3;                       // wave-uniform
    const int s    = ((wv & 7) << 6) | lane;
    const int i0   = half * 64;

    const float* __restrict__ rp0 = rowpack + t * (DLAT * 48) + i0 * 48;  // uniform

    v2f dot[8], prod[8];
    #pragma unroll
    for (int q = 0; q < 8; q++) { dot[q] = (v2f)(0.f); prod[q] = (v2f)(1.f); }

    #pragma unroll 2
    for (int ii = 0; ii < 64; ii++) {
        float4 sc = scd[(i0 + ii) * NSUP + s];
        v2f sv = {sc.x, sc.x}, cv = {sc.y, sc.y}, dv = {sc.z, sc.z};
        const float* rp = rp0 + ii * 48;            // uniform -> 3x s_load_dwordx16
        #pragma unroll
        for (int q = 0; q < 8; q++) {
            v2f lv = {rp[2 * q],      rp[2 * q + 1]};
            v2f av = {rp[16 + 2 * q], rp[16 + 2 * q + 1]};
            v2f bv = {rp[32 + 2 * q], rp[32 + 2 * q + 1]};
            dot[q]  = __builtin_elementwise_fma(lv, sv, dot[q]);
            v2f tt  = __builtin_elementwise_fma(av, cv, bv * dv);
            prod[q] = prod[q] * tt;
        }
    }

    if (half) {
        #pragma unroll
        for (int q = 0; q < 8; q++) {
            comb[s][2 * q]          = dot[q].x;
            comb[s][2 * q + 1]      = dot[q].y;
            comb[s][16 + 2 * q]     = prod[q].x;
            comb[s][16 + 2 * q + 1] = prod[q].y;
        }
    }
    __syncthreads();

    if (!half) {
        float dfull[BR], pfull[BR];
        #pragma unroll
        for (int q = 0; q < 8; q++) {
            dfull[2 * q]     = dot[q].x + comb[s][2 * q];
            dfull[2 * q + 1] = dot[q].y + comb[s][2 * q + 1];
            pfull[2 * q]     = prod[q].x * comb[s][16 + 2 * q];
            pfull[2 * q + 1] = prod[q].y * comb[s][16 + 2 * q + 1];
        }
        float sn  = sn2[s];
        float wgt = wts[s];
        const float* lr = ln2s + t * BR;            // uniform
        #pragma unroll
        for (int r = 0; r < BR; r++) {
            float sq = lr[r] + sn - 2.f * dfull[r];
            float kc = __expf(-sq);
            float p  = pfull[r];
            float v  = (0.5f * kc + 0.5f * (p * p)) * wgt;
            for (int off = 32; off; off >>= 1) v += __shfl_down(v, off);
            if (lane == 0) redw[wv][r] = v;
        }
    }
    __syncthreads();
    if (threadIdx.x < BR) {
        float o = 0.f;
        #pragma unroll
        for (int w = 0; w < 8; w++) o += redw[w][threadIdx.x];
        out[t * BR + threadIdx.x] = o;
    }
}

// ---------------- launch ----------------
extern "C" void kernel_launch(void* const* d_in, const int* in_sizes, int n_in,
                              void* d_out, int out_size, void* d_ws, size_t ws_size,
                              hipStream_t stream) {
    const float* x       = (const float*)d_in[0];
    const float* W1      = (const float*)d_in[1];
    const float* b1      = (const float*)d_in[2];
    const float* W2      = (const float*)d_in[3];
    const float* b2      = (const float*)d_in[4];
    const float* support = (const float*)d_in[5];
    const float* wts     = (const float*)d_in[6];
    float* out = (float*)d_out;

    float* ws      = (float*)d_ws;
    float* W1T     = ws;                        // 32768
    float* W2T     = W1T + 32768;               // 65536
    float* xpack   = W2T + 65536;               // 262144
    float* hpack   = xpack + 262144;            // 2097152
    float* rowpack = hpack + 2097152;           // 1572864
    float* ln2s    = rowpack + 1572864;         // 4096
    float* sn2     = ln2s + 4096;               // 512
    float4* scd    = (float4*)(sn2 + 512);      // 65536 float4 (16B-aligned offset)

    prep_kernel <<<512,  512, 0, stream>>>(x, W1, W2, support, W1T, W2T, xpack, scd, sn2);
    gemm1_kernel<<<NTILE, 1024, 0, stream>>>(W1T, b1, xpack, hpack);
    gemm2_kernel<<<NTILE, 1024, 0, stream>>>(W2T, b2, hpack, rowpack, ln2s);
    kernelB     <<<NTILE, 1024, 0, stream>>>(scd, sn2, wts, rowpack, ln2s, out);
}